// Round 26
// baseline (193.324 us; speedup 1.0000x reference)
//
#include <hip/hip_runtime.h>

#define TSTEPS 20
#define THRESV 1.0f
#define DECAYV 0.9375f

// Dense paths: row-block partials + step sums + layer-1 masks.
__device__ float g_part1[16][20][8192];  // 10.5 MB (rb = 192-row blocks)
__device__ float g_sum1[TSTEPS][8192];   // 640 KB
__device__ unsigned g_mask2[8192];       // 19-bit masks (layer-1 spikes)
__device__ float g_part2[32][19][8192];  // 20 MB  (rb = 256-row blocks)
__device__ float g_sum2[TSTEPS][8192];   // 640 KB ([0] unused)
__device__ float g_sum3[TSTEPS][16];     // [0] unused

// ws byte layout:
//   [0, 20480)   u64 s2_bits[20][128]   (row 0 zeroed by lif2 each launch)

struct __align__(16) SMem {
    unsigned short list[8192];      // firing-row indices (W3 path)
    float partials[512];            // [32][16] (W3 path)
    unsigned long long bw[128];
    unsigned pc[128];
    int cntp;
};

// Deterministic parallel compaction (ascending list order, bitwise-stable).
template <int NW>
__device__ __forceinline__ int compact_par(const unsigned long long* bits, SMem& sm) {
    int tid = threadIdx.x;
    if (tid < NW) {
        unsigned long long w = bits[tid];
        sm.bw[tid] = w;
        sm.pc[tid] = (unsigned)__popcll(w);
    }
    __syncthreads();
    constexpr int WPW = NW / 8;
    int wave = tid >> 6, lane = tid & 63;
    int w0 = wave * WPW;
    int base = 0;
    for (int i = lane; i < w0; i += 64) base += (int)sm.pc[i];
    #pragma unroll
    for (int off = 1; off < 64; off <<= 1) base += __shfl_xor(base, off);
    if (wave == 0) {
        int tot = 0;
        for (int i = lane; i < NW; i += 64) tot += (int)sm.pc[i];
        #pragma unroll
        for (int off = 1; off < 64; off <<= 1) tot += __shfl_xor(tot, off);
        if (lane == 0) sm.cntp = tot;
    }
    for (int i = 0; i < WPW; ++i) {
        unsigned long long w = sm.bw[w0 + i];
        if ((w >> lane) & 1ull) {
            int pos = base + __popcll(w & ((1ull << lane) - 1ull));
            sm.list[pos] = (unsigned short)(((w0 + i) << 6) + lane);
        }
        base += __popcll(w);
    }
    __syncthreads();
    return sm.cntp;
}

#define GLD1(dst, ptr) \
    asm volatile("global_load_dword %0, %1, off" : "=v"(dst) : "v"(ptr))
#define WAIT8(a0,a1,a2,a3,a4,a5,a6,a7) \
    asm volatile("s_waitcnt vmcnt(0)" \
        : "+v"(a0),"+v"(a1),"+v"(a2),"+v"(a3),"+v"(a4),"+v"(a5),"+v"(a6),"+v"(a7))

__device__ __forceinline__ void accr20(float w, unsigned m, float* ax) {
    #pragma unroll
    for (int bb = 0; bb < 20; ++bb)
        if (m & (1u << bb)) ax[bb] += w;
}
__device__ __forceinline__ void accr19(float w, unsigned m, float* ax) {
    #pragma unroll
    for (int bb = 0; bb < 19; ++bb)
        if (m & (1u << bb)) ax[bb] += w;
}

// B': stream W1 exactly once; input-IF mask fused. 16 cs x 16 rb = 256 blocks,
// 512 thr x 1 col (dword). Rows 0..191 ascending per block; reduce ascending
// rb => canonical rows-ascending order (validated association class).
__global__ void __launch_bounds__(512)
w1_dense_kernel(const float* __restrict__ W1, const float* __restrict__ image) {
    __shared__ unsigned msk[192];
    int blk = blockIdx.x;
    int cs = blk >> 4;                               // 0..15
    int rb = blk & 15;                               // 0..15
    int tid = threadIdx.x;
    if (tid < 192) {
        float img = image[rb * 192 + tid];
        float mi = 0.f;
        unsigned mask = 0;
        #pragma unroll
        for (int t = 0; t < TSTEPS; ++t) {
            mi += img;
            bool fire = (mi >= THRESV);
            if (fire) mi -= THRESV;
            mask |= (unsigned)fire << t;
        }
        msk[tid] = mask;
    }
    __syncthreads();
    int j = cs * 512 + tid;
    const float* Wp = W1 + (size_t)rb * 192 * 8192 + j;
    float ax[20];
    #pragma unroll
    for (int b = 0; b < 20; ++b) ax[b] = 0.f;
    for (int r = 0; r < 192; r += 8) {
        const float* p = Wp + (size_t)r * 8192;
        float w0, w1, w2, w3, w4, w5, w6, w7;
        GLD1(w0, p);                GLD1(w1, p + 8192);
        GLD1(w2, p + 2 * 8192);     GLD1(w3, p + 3 * 8192);
        GLD1(w4, p + 4 * 8192);     GLD1(w5, p + 5 * 8192);
        GLD1(w6, p + 6 * 8192);     GLD1(w7, p + 7 * 8192);
        WAIT8(w0, w1, w2, w3, w4, w5, w6, w7);
        accr20(w0, __builtin_amdgcn_readfirstlane(msk[r    ]), ax);
        accr20(w1, __builtin_amdgcn_readfirstlane(msk[r + 1]), ax);
        accr20(w2, __builtin_amdgcn_readfirstlane(msk[r + 2]), ax);
        accr20(w3, __builtin_amdgcn_readfirstlane(msk[r + 3]), ax);
        accr20(w4, __builtin_amdgcn_readfirstlane(msk[r + 4]), ax);
        accr20(w5, __builtin_amdgcn_readfirstlane(msk[r + 5]), ax);
        accr20(w6, __builtin_amdgcn_readfirstlane(msk[r + 6]), ax);
        accr20(w7, __builtin_amdgcn_readfirstlane(msk[r + 7]), ax);
    }
    #pragma unroll
    for (int b = 0; b < 20; ++b)
        g_part1[rb][b][j] = ax[b];
}

// R1: reduce the 16 row-block partials (ascending rb) -> g_sum1[t].
__global__ void __launch_bounds__(512)
w1_reduce_kernel() {
    int b = blockIdx.x;                              // 20 t x 16 col-chunks
    int t = b / 16;
    int j = (b % 16) * 512 + threadIdx.x;
    float s = 0.f;
    #pragma unroll 8
    for (int rb = 0; rb < 16; ++rb)
        s += g_part1[rb][t][j];
    g_sum1[t][j] = s;
}

// C': thin LIF chain layer 1 -> g_mask2 directly.
__global__ void __launch_bounds__(512)
lif1_kernel() {
    int j = blockIdx.x * 512 + threadIdx.x;          // 0..8191
    float m = 0.f;
    unsigned mask = 0;
    #pragma unroll
    for (int t = 0; t < TSTEPS; ++t) {
        float v = m + g_sum1[t][j];
        bool fire = (v >= THRESV);
        if (fire) v -= THRESV;
        m = fire ? v : v * DECAYV;
        mask |= (unsigned)fire << t;
    }
    g_mask2[j] = mask;                               // bits 0..18 used by D'
}

// D': stream W2 exactly once; 16 cs x 32 rb = 512 blocks (2/CU), 512 thr x
// 1 col (dword), 256 rows/block ascending; reduce ascending rb.
__global__ void __launch_bounds__(512)
w2_dense_kernel(const float* __restrict__ W2) {
    __shared__ unsigned msk[256];
    int blk = blockIdx.x;
    int cs = blk >> 5;                               // 0..15
    int rb = blk & 31;                               // 0..31
    int tid = threadIdx.x;
    if (tid < 256) msk[tid] = g_mask2[rb * 256 + tid];
    __syncthreads();
    int j = cs * 512 + tid;
    const float* Wp = W2 + (size_t)rb * 256 * 8192 + j;
    float ax[19];
    #pragma unroll
    for (int b = 0; b < 19; ++b) ax[b] = 0.f;
    for (int r = 0; r < 256; r += 8) {
        const float* p = Wp + (size_t)r * 8192;
        float w0, w1, w2, w3, w4, w5, w6, w7;
        GLD1(w0, p);                GLD1(w1, p + 8192);
        GLD1(w2, p + 2 * 8192);     GLD1(w3, p + 3 * 8192);
        GLD1(w4, p + 4 * 8192);     GLD1(w5, p + 5 * 8192);
        GLD1(w6, p + 6 * 8192);     GLD1(w7, p + 7 * 8192);
        WAIT8(w0, w1, w2, w3, w4, w5, w6, w7);
        accr19(w0, __builtin_amdgcn_readfirstlane(msk[r    ]), ax);
        accr19(w1, __builtin_amdgcn_readfirstlane(msk[r + 1]), ax);
        accr19(w2, __builtin_amdgcn_readfirstlane(msk[r + 2]), ax);
        accr19(w3, __builtin_amdgcn_readfirstlane(msk[r + 3]), ax);
        accr19(w4, __builtin_amdgcn_readfirstlane(msk[r + 4]), ax);
        accr19(w5, __builtin_amdgcn_readfirstlane(msk[r + 5]), ax);
        accr19(w6, __builtin_amdgcn_readfirstlane(msk[r + 6]), ax);
        accr19(w7, __builtin_amdgcn_readfirstlane(msk[r + 7]), ax);
    }
    #pragma unroll
    for (int b = 0; b < 19; ++b)
        g_part2[rb][b][j] = ax[b];
}

// R2: reduce the 32 row-block partials (ascending rb) -> g_sum2[t].
__global__ void __launch_bounds__(512)
w2_reduce_kernel() {
    int b = blockIdx.x;                              // 19 t x 16 col-chunks
    int t = 1 + b / 16;
    int j = (b % 16) * 512 + threadIdx.x;
    float s = 0.f;
    #pragma unroll 8
    for (int rb = 0; rb < 32; ++rb)
        s += g_part2[rb][t - 1][j];
    g_sum2[t][j] = s;
}

// E': thin LIF chain layer 2 -> s2 ballot bits; also zeroes row 0.
__global__ void __launch_bounds__(512)
lif2_kernel(unsigned long long* __restrict__ s2_bits) {
    int j = blockIdx.x * 512 + threadIdx.x;          // 0..8191
    int lane = threadIdx.x & 63;
    if (lane == 0) s2_bits[j >> 6] = 0ull;           // row 0 = no spikes
    float m = 0.f;
    for (int t = 1; t < TSTEPS; ++t) {
        float v = m + g_sum2[t][j];
        bool fire = (v >= THRESV);
        if (fire) v -= THRESV;
        m = fire ? v : v * DECAYV;
        unsigned long long bm = __ballot(fire);
        if (lane == 0) s2_bits[(size_t)t * 128 + (j >> 6)] = bm;
    }
}

// F1: per-step W3 gather sums (19 parallel blocks, one per step).
__global__ void __launch_bounds__(512)
w3_sums_kernel(const float* __restrict__ W3,
               const unsigned long long* __restrict__ s2_bits) {
    __shared__ SMem sm;
    int t = blockIdx.x + 1;                          // 1..19
    int tid = threadIdx.x;
    int count = compact_par<128>(s2_bits + (size_t)(t - 1) * 128, sm);
    int col = tid & 15, g = tid >> 4;                // g 0..31
    float acc = 0.f;
    if (col < 10) {
        for (int k = g; k < count; k += 32)
            acc += W3[(size_t)sm.list[k] * 10 + col];
    }
    sm.partials[g * 16 + col] = acc;
    __syncthreads();
    if (tid < 10) {
        float s = 0.f;
        for (int gg = 0; gg < 32; ++gg) s += sm.partials[gg * 16 + tid];
        g_sum3[t][tid] = s;
    }
}

// F2: 10-neuron LIF chain; also zeroes output rows 0,1.
__global__ void w3_lif_kernel(float* __restrict__ out) {
    int tid = threadIdx.x;
    if (tid < 10) {
        out[tid] = 0.f;
        out[10 + tid] = 0.f;
        float m = 0.f;
        for (int t = 1; t < TSTEPS; ++t) {
            float v = m + g_sum3[t][tid];
            bool fire = (v >= THRESV);
            if (fire) v -= THRESV;
            m = fire ? v : v * DECAYV;
            out[(t + 1) * 10 + tid] = fire ? 1.f : 0.f;
        }
    }
}

extern "C" void kernel_launch(void* const* d_in, const int* in_sizes, int n_in,
                              void* d_out, int out_size, void* d_ws, size_t ws_size,
                              hipStream_t stream) {
    const float* image = (const float*)d_in[0];
    const float* W1 = (const float*)d_in[1];
    const float* W2 = (const float*)d_in[2];
    const float* W3 = (const float*)d_in[3];
    float* out = (float*)d_out;

    unsigned long long* s2_bits = (unsigned long long*)d_ws;   // [20][128]

    // B': dense single-pass W1 accumulation (input-IF fused; 256 blocks)
    w1_dense_kernel<<<16 * 16, 512, 0, stream>>>(W1, image);
    // R1: parallel reduce -> g_sum1 (320 blocks)
    w1_reduce_kernel<<<20 * 16, 512, 0, stream>>>();
    // C': thin LIF chain layer 1 -> g_mask2
    lif1_kernel<<<16, 512, 0, stream>>>();
    // D': dense single-pass W2 accumulation (512 blocks)
    w2_dense_kernel<<<16 * 32, 512, 0, stream>>>(W2);
    // R2: parallel reduce -> g_sum2 (304 blocks)
    w2_reduce_kernel<<<19 * 16, 512, 0, stream>>>();
    // E': thin LIF chain layer 2 -> s2 bits (zeroes row 0 itself)
    lif2_kernel<<<16, 512, 0, stream>>>(s2_bits);
    // F1: per-step W3 gather sums
    w3_sums_kernel<<<TSTEPS - 1, 512, 0, stream>>>(W3, s2_bits);
    // F2: 10-neuron LIF chain -> output rows (zeroes rows 0,1 itself)
    w3_lif_kernel<<<1, 64, 0, stream>>>(out);
}

// Round 27
// 153.384 us; speedup vs baseline: 1.2604x; 1.2604x over previous
//
#include <hip/hip_runtime.h>

#define TSTEPS 20
#define THRESV 1.0f
#define DECAYV 0.9375f

typedef float f32x2 __attribute__((ext_vector_type(2)));

// Dense paths: row-block partials + step sums + layer-1 masks.
__device__ float g_part1[32][20][8192];  // 21 MB  (rb = 96-row blocks)
__device__ float g_sum1[TSTEPS][8192];   // 640 KB
__device__ unsigned g_mask2[8192];       // 19-bit masks (layer-1 spikes)
__device__ float g_part2[64][19][8192];  // 40 MB  (rb = 128-row blocks)
__device__ float g_sum2[TSTEPS][8192];   // 640 KB ([0] unused)
__device__ float g_sum3[TSTEPS][16];     // [0] unused

// ws byte layout:
//   [0, 20480)   u64 s2_bits[20][128]   (row 0 zeroed by lif2 each launch)

struct __align__(16) SMem {
    unsigned short list[8192];      // firing-row indices (W3 path)
    float partials[512];            // [32][16] (W3 path)
    unsigned long long bw[128];
    unsigned pc[128];
    int cntp;
};

// Deterministic parallel compaction (ascending list order, bitwise-stable).
template <int NW>
__device__ __forceinline__ int compact_par(const unsigned long long* bits, SMem& sm) {
    int tid = threadIdx.x;
    if (tid < NW) {
        unsigned long long w = bits[tid];
        sm.bw[tid] = w;
        sm.pc[tid] = (unsigned)__popcll(w);
    }
    __syncthreads();
    constexpr int WPW = NW / 8;
    int wave = tid >> 6, lane = tid & 63;
    int w0 = wave * WPW;
    int base = 0;
    for (int i = lane; i < w0; i += 64) base += (int)sm.pc[i];
    #pragma unroll
    for (int off = 1; off < 64; off <<= 1) base += __shfl_xor(base, off);
    if (wave == 0) {
        int tot = 0;
        for (int i = lane; i < NW; i += 64) tot += (int)sm.pc[i];
        #pragma unroll
        for (int off = 1; off < 64; off <<= 1) tot += __shfl_xor(tot, off);
        if (lane == 0) sm.cntp = tot;
    }
    for (int i = 0; i < WPW; ++i) {
        unsigned long long w = sm.bw[w0 + i];
        if ((w >> lane) & 1ull) {
            int pos = base + __popcll(w & ((1ull << lane) - 1ull));
            sm.list[pos] = (unsigned short)(((w0 + i) << 6) + lane);
        }
        base += __popcll(w);
    }
    __syncthreads();
    return sm.cntp;
}

#define GLD2(dst, ptr) \
    asm volatile("global_load_dwordx2 %0, %1, off" : "=v"(dst) : "v"(ptr))
#define WAIT8(a0,a1,a2,a3,a4,a5,a6,a7) \
    asm volatile("s_waitcnt vmcnt(0)" \
        : "+v"(a0),"+v"(a1),"+v"(a2),"+v"(a3),"+v"(a4),"+v"(a5),"+v"(a6),"+v"(a7))

__device__ __forceinline__ void accrow20(f32x2 w, unsigned m, float* ax, float* ay) {
    #pragma unroll
    for (int bb = 0; bb < 20; ++bb)
        if (m & (1u << bb)) { ax[bb] += w.x; ay[bb] += w.y; }
}

// B': stream W1 exactly once; input-IF mask computation fused in (identical
// arithmetic chain per row => identical masks => bitwise-identical partials).
__global__ void __launch_bounds__(512)
w1_dense_kernel(const float* __restrict__ W1, const float* __restrict__ image) {
    __shared__ unsigned msk[96];
    int blk = blockIdx.x;
    int cs = blk >> 5;                               // 0..7
    int rb = blk & 31;                               // 0..31
    int tid = threadIdx.x;
    if (tid < 96) {
        float img = image[rb * 96 + tid];
        float mi = 0.f;
        unsigned mask = 0;
        #pragma unroll
        for (int t = 0; t < TSTEPS; ++t) {
            mi += img;
            bool fire = (mi >= THRESV);
            if (fire) mi -= THRESV;
            mask |= (unsigned)fire << t;
        }
        msk[tid] = mask;
    }
    __syncthreads();
    int j = cs * 1024 + tid * 2;
    const float* Wp = W1 + (size_t)rb * 96 * 8192 + j;
    float ax[20], ay[20];
    #pragma unroll
    for (int b = 0; b < 20; ++b) { ax[b] = 0.f; ay[b] = 0.f; }
    for (int r = 0; r < 96; r += 8) {
        const float* p = Wp + (size_t)r * 8192;
        f32x2 w0, w1, w2, w3, w4, w5, w6, w7;
        GLD2(w0, p);                GLD2(w1, p + 8192);
        GLD2(w2, p + 2 * 8192);     GLD2(w3, p + 3 * 8192);
        GLD2(w4, p + 4 * 8192);     GLD2(w5, p + 5 * 8192);
        GLD2(w6, p + 6 * 8192);     GLD2(w7, p + 7 * 8192);
        WAIT8(w0, w1, w2, w3, w4, w5, w6, w7);
        accrow20(w0, __builtin_amdgcn_readfirstlane(msk[r    ]), ax, ay);
        accrow20(w1, __builtin_amdgcn_readfirstlane(msk[r + 1]), ax, ay);
        accrow20(w2, __builtin_amdgcn_readfirstlane(msk[r + 2]), ax, ay);
        accrow20(w3, __builtin_amdgcn_readfirstlane(msk[r + 3]), ax, ay);
        accrow20(w4, __builtin_amdgcn_readfirstlane(msk[r + 4]), ax, ay);
        accrow20(w5, __builtin_amdgcn_readfirstlane(msk[r + 5]), ax, ay);
        accrow20(w6, __builtin_amdgcn_readfirstlane(msk[r + 6]), ax, ay);
        accrow20(w7, __builtin_amdgcn_readfirstlane(msk[r + 7]), ax, ay);
    }
    #pragma unroll
    for (int b = 0; b < 20; ++b)
        *(f32x2*)&g_part1[rb][b][j] = (f32x2){ax[b], ay[b]};
}

// R1: reduce the 32 row-block partials (ascending rb) -> g_sum1[t].
__global__ void __launch_bounds__(512)
w1_reduce_kernel() {
    int b = blockIdx.x;                              // 20 t x 16 col-chunks
    int t = b / 16;
    int j = (b % 16) * 512 + threadIdx.x;
    float s = 0.f;
    #pragma unroll 8
    for (int rb = 0; rb < 32; ++rb)
        s += g_part1[rb][t][j];
    g_sum1[t][j] = s;
}

// C': thin LIF chain layer 1 -> g_mask2 directly.
__global__ void __launch_bounds__(512)
lif1_kernel() {
    int j = blockIdx.x * 512 + threadIdx.x;          // 0..8191
    float m = 0.f;
    unsigned mask = 0;
    #pragma unroll
    for (int t = 0; t < TSTEPS; ++t) {
        float v = m + g_sum1[t][j];
        bool fire = (v >= THRESV);
        if (fire) v -= THRESV;
        m = fire ? v : v * DECAYV;
        mask |= (unsigned)fire << t;
    }
    g_mask2[j] = mask;                               // bits 0..18 used by D'
}

__device__ __forceinline__ void accrow19(f32x2 w, unsigned m, float* ax, float* ay) {
    #pragma unroll
    for (int bb = 0; bb < 19; ++bb)
        if (m & (1u << bb)) { ax[bb] += w.x; ay[bb] += w.y; }
}

// D': stream W2 exactly once; dwordx2, rb = 128-row blocks (8 cs x 64 rb =
// 512 blocks, 2/CU) — the r23/r25-validated geometry.
__global__ void __launch_bounds__(512)
w2_dense_kernel(const float* __restrict__ W2) {
    __shared__ unsigned msk[128];
    int blk = blockIdx.x;
    int cs = blk >> 6;                               // 0..7
    int rb = blk & 63;                               // 0..63
    int tid = threadIdx.x;
    if (tid < 128) msk[tid] = g_mask2[rb * 128 + tid];
    __syncthreads();
    int j = cs * 1024 + tid * 2;
    const float* Wp = W2 + (size_t)rb * 128 * 8192 + j;
    float ax[19], ay[19];
    #pragma unroll
    for (int b = 0; b < 19; ++b) { ax[b] = 0.f; ay[b] = 0.f; }
    for (int r = 0; r < 128; r += 8) {
        const float* p = Wp + (size_t)r * 8192;
        f32x2 w0, w1, w2, w3, w4, w5, w6, w7;
        GLD2(w0, p);                GLD2(w1, p + 8192);
        GLD2(w2, p + 2 * 8192);     GLD2(w3, p + 3 * 8192);
        GLD2(w4, p + 4 * 8192);     GLD2(w5, p + 5 * 8192);
        GLD2(w6, p + 6 * 8192);     GLD2(w7, p + 7 * 8192);
        WAIT8(w0, w1, w2, w3, w4, w5, w6, w7);
        accrow19(w0, __builtin_amdgcn_readfirstlane(msk[r    ]), ax, ay);
        accrow19(w1, __builtin_amdgcn_readfirstlane(msk[r + 1]), ax, ay);
        accrow19(w2, __builtin_amdgcn_readfirstlane(msk[r + 2]), ax, ay);
        accrow19(w3, __builtin_amdgcn_readfirstlane(msk[r + 3]), ax, ay);
        accrow19(w4, __builtin_amdgcn_readfirstlane(msk[r + 4]), ax, ay);
        accrow19(w5, __builtin_amdgcn_readfirstlane(msk[r + 5]), ax, ay);
        accrow19(w6, __builtin_amdgcn_readfirstlane(msk[r + 6]), ax, ay);
        accrow19(w7, __builtin_amdgcn_readfirstlane(msk[r + 7]), ax, ay);
    }
    #pragma unroll
    for (int b = 0; b < 19; ++b)
        *(f32x2*)&g_part2[rb][b][j] = (f32x2){ax[b], ay[b]};
}

// R2: reduce the 64 row-block partials (ascending rb) -> g_sum2[t].
__global__ void __launch_bounds__(512)
w2_reduce_kernel() {
    int b = blockIdx.x;                              // 19 t x 16 col-chunks
    int t = 1 + b / 16;
    int j = (b % 16) * 512 + threadIdx.x;
    float s = 0.f;
    #pragma unroll 8
    for (int rb = 0; rb < 64; ++rb)
        s += g_part2[rb][t - 1][j];
    g_sum2[t][j] = s;
}

// E': thin LIF chain layer 2 -> s2 ballot bits; also zeroes row 0.
__global__ void __launch_bounds__(512)
lif2_kernel(unsigned long long* __restrict__ s2_bits) {
    int j = blockIdx.x * 512 + threadIdx.x;          // 0..8191
    int lane = threadIdx.x & 63;
    if (lane == 0) s2_bits[j >> 6] = 0ull;           // row 0 = no spikes
    float m = 0.f;
    for (int t = 1; t < TSTEPS; ++t) {
        float v = m + g_sum2[t][j];
        bool fire = (v >= THRESV);
        if (fire) v -= THRESV;
        m = fire ? v : v * DECAYV;
        unsigned long long bm = __ballot(fire);
        if (lane == 0) s2_bits[(size_t)t * 128 + (j >> 6)] = bm;
    }
}

// F1: per-step W3 gather sums (19 parallel blocks, one per step).
__global__ void __launch_bounds__(512)
w3_sums_kernel(const float* __restrict__ W3,
               const unsigned long long* __restrict__ s2_bits) {
    __shared__ SMem sm;
    int t = blockIdx.x + 1;                          // 1..19
    int tid = threadIdx.x;
    int count = compact_par<128>(s2_bits + (size_t)(t - 1) * 128, sm);
    int col = tid & 15, g = tid >> 4;                // g 0..31
    float acc = 0.f;
    if (col < 10) {
        for (int k = g; k < count; k += 32)
            acc += W3[(size_t)sm.list[k] * 10 + col];
    }
    sm.partials[g * 16 + col] = acc;
    __syncthreads();
    if (tid < 10) {
        float s = 0.f;
        for (int gg = 0; gg < 32; ++gg) s += sm.partials[gg * 16 + tid];
        g_sum3[t][tid] = s;
    }
}

// F2: 10-neuron LIF chain; also zeroes output rows 0,1.
__global__ void w3_lif_kernel(float* __restrict__ out) {
    int tid = threadIdx.x;
    if (tid < 10) {
        out[tid] = 0.f;
        out[10 + tid] = 0.f;
        float m = 0.f;
        for (int t = 1; t < TSTEPS; ++t) {
            float v = m + g_sum3[t][tid];
            bool fire = (v >= THRESV);
            if (fire) v -= THRESV;
            m = fire ? v : v * DECAYV;
            out[(t + 1) * 10 + tid] = fire ? 1.f : 0.f;
        }
    }
}

extern "C" void kernel_launch(void* const* d_in, const int* in_sizes, int n_in,
                              void* d_out, int out_size, void* d_ws, size_t ws_size,
                              hipStream_t stream) {
    const float* image = (const float*)d_in[0];
    const float* W1 = (const float*)d_in[1];
    const float* W2 = (const float*)d_in[2];
    const float* W3 = (const float*)d_in[3];
    float* out = (float*)d_out;

    unsigned long long* s2_bits = (unsigned long long*)d_ws;   // [20][128]

    // B': dense single-pass W1 accumulation (input-IF fused; 256 blocks)
    w1_dense_kernel<<<8 * 32, 512, 0, stream>>>(W1, image);
    // R1: parallel reduce -> g_sum1 (320 blocks)
    w1_reduce_kernel<<<20 * 16, 512, 0, stream>>>();
    // C': thin LIF chain layer 1 -> g_mask2
    lif1_kernel<<<16, 512, 0, stream>>>();
    // D': dense single-pass W2 accumulation (dwordx2; 512 blocks)
    w2_dense_kernel<<<8 * 64, 512, 0, stream>>>(W2);
    // R2: parallel reduce -> g_sum2 (304 blocks)
    w2_reduce_kernel<<<19 * 16, 512, 0, stream>>>();
    // E': thin LIF chain layer 2 -> s2 bits (zeroes row 0 itself)
    lif2_kernel<<<16, 512, 0, stream>>>(s2_bits);
    // F1: per-step W3 gather sums
    w3_sums_kernel<<<TSTEPS - 1, 512, 0, stream>>>(W3, s2_bits);
    // F2: 10-neuron LIF chain -> output rows (zeroes rows 0,1 itself)
    w3_lif_kernel<<<1, 64, 0, stream>>>(out);
}